// Round 1
// baseline (6283.144 us; speedup 1.0000x reference)
//
#include <hip/hip_runtime.h>
#include <hip/hip_bf16.h>
#include <math.h>

// SAM vision layer: LN1 -> windowed attention (decomposed rel-pos bias) -> proj
// + residual -> LN2 -> MLP(GELU exact) -> residual.
// B=8, H=W=64, HS=768, NH=12, HD=64, WS=14 -> 200 windows x 196 tokens.

#define HS 768
#define NHEADS 12
#define HD 64
#define WSZ 14
#define TOK 196
#define HWDIM 64
#define NSIDE 5
#define WIN_PER_B 25
#define WCHUNK 25
#define MCH 4900        // rows per window chunk = 25*196
#define MLPCH 8192      // tokens per MLP chunk (32768/4)

typedef __attribute__((ext_vector_type(8))) short short8;
typedef __attribute__((ext_vector_type(4))) float floatx4;

__device__ __forceinline__ float bf2f(unsigned short u) {
    union { unsigned int i; float f; } w; w.i = ((unsigned int)u) << 16; return w.f;
}

// ---- fp32 -> bf16 transposed convert: src[K][N] -> dst[N][K] ----
__global__ __launch_bounds__(256)
void cvt_t_k(const float* __restrict__ src, __hip_bfloat16* __restrict__ dst,
             int K, int N) {
    int idx = blockIdx.x * 256 + threadIdx.x;
    if (idx >= K * N) return;
    int k = idx / N, n = idx - k * N;
    dst[(size_t)n * K + k] = __float2bfloat16(src[idx]);
}

// ---- LayerNorm over HS=768, one block per row, 256 threads (3 elems each) ----
__global__ __launch_bounds__(256)
void ln_k(const float* __restrict__ x, const float* __restrict__ g,
          const float* __restrict__ b, __hip_bfloat16* __restrict__ y) {
    int row = blockIdx.x;
    const float* xr = x + (size_t)row * HS;
    int tid = threadIdx.x;
    float v0 = xr[tid], v1 = xr[tid + 256], v2 = xr[tid + 512];
    float s = v0 + v1 + v2;
    float q = v0 * v0 + v1 * v1 + v2 * v2;
    for (int off = 32; off > 0; off >>= 1) {
        s += __shfl_down(s, off, 64);
        q += __shfl_down(q, off, 64);
    }
    __shared__ float ss[4], sq[4];
    int wave = tid >> 6, lane = tid & 63;
    if (lane == 0) { ss[wave] = s; sq[wave] = q; }
    __syncthreads();
    if (tid == 0) {
        float S = ss[0] + ss[1] + ss[2] + ss[3];
        float Q = sq[0] + sq[1] + sq[2] + sq[3];
        float mu = S * (1.0f / HS);
        float var = Q * (1.0f / HS) - mu * mu;
        ss[0] = mu;
        sq[0] = rsqrtf(var + 1e-6f);
    }
    __syncthreads();
    float mu = ss[0], rstd = sq[0];
    __hip_bfloat16* yr = y + (size_t)row * HS;
    yr[tid]       = __float2bfloat16((v0 - mu) * rstd * g[tid]       + b[tid]);
    yr[tid + 256] = __float2bfloat16((v1 - mu) * rstd * g[tid + 256] + b[tid + 256]);
    yr[tid + 512] = __float2bfloat16((v2 - mu) * rstd * g[tid + 512] + b[tid + 512]);
}

// ---- Generic bf16 MFMA GEMM, 64x64 tile, 4 waves (each: 16 rows x 64 cols).
// A: MxK row-major bf16 (AGATHER=1: M indexes window tokens gathered from y
// with zero pad). Bt: NxK row-major bf16 (weights pre-transposed).
// EP: 0=qkv head-scatter(bf16)  1=proj+residual+window-unpartition(fp32)
//     2=GELU->bf16 hidden       3=add into out(fp32)
template<int EP, int AGATHER>
__global__ __launch_bounds__(256)
void gemm_k(const __hip_bfloat16* __restrict__ A,
            const __hip_bfloat16* __restrict__ Bt,
            const float* __restrict__ bias,
            int M, int N, int K,
            __hip_bfloat16* __restrict__ oq, __hip_bfloat16* __restrict__ okk,
            __hip_bfloat16* __restrict__ ov,
            float* __restrict__ of, const float* __restrict__ resid,
            __hip_bfloat16* __restrict__ oh,
            int win_base, int m_base)
{
    __shared__ unsigned short As[64 * 32];
    __shared__ unsigned short Bs[64 * 32];
    __shared__ int rowsrc[64];

    int tid = threadIdx.x;
    int bm = blockIdx.x * 64;
    int bn = blockIdx.y * 64;
    int wave = tid >> 6, lane = tid & 63;

    if (tid < 64) {
        int m = bm + tid;
        int src = -1;
        if (m < M) {
            if (AGATHER) {
                int lwin = m / TOK, tok = m - lwin * TOK;
                int win = win_base + lwin;
                int bb = win / WIN_PER_B, r = win - bb * WIN_PER_B;
                int wi = r / NSIDE, wj = r - wi * NSIDE;
                int ti = tok / WSZ, tj = tok - ti * WSZ;
                int h = wi * WSZ + ti, w = wj * WSZ + tj;
                if (h < HWDIM && w < HWDIM) src = (bb * HWDIM + h) * HWDIM + w;
            } else {
                src = m;
            }
        }
        rowsrc[tid] = src;
    }
    __syncthreads();

    int smm = tid >> 2;
    int sk8 = (tid & 3) * 8;
    int asrc = rowsrc[smm];
    const unsigned short* Au = (const unsigned short*)A;
    const unsigned short* Bu = (const unsigned short*)Bt;

    floatx4 acc0 = {0.f, 0.f, 0.f, 0.f}, acc1 = acc0, acc2 = acc0, acc3 = acc0;

    int arow = wave * 16 + (lane & 15);
    int kq8 = (lane >> 4) * 8;

    for (int k0 = 0; k0 < K; k0 += 32) {
        uint4 av = {0u, 0u, 0u, 0u};
        if (asrc >= 0) av = *(const uint4*)(Au + (size_t)asrc * K + k0 + sk8);
        uint4 bv = *(const uint4*)(Bu + (size_t)(bn + smm) * K + k0 + sk8);
        __syncthreads();
        *(uint4*)&As[smm * 32 + sk8] = av;
        *(uint4*)&Bs[smm * 32 + sk8] = bv;
        __syncthreads();
        short8 af = *(const short8*)&As[arow * 32 + kq8];
        short8 b0 = *(const short8*)&Bs[( 0 + (lane & 15)) * 32 + kq8];
        short8 b1 = *(const short8*)&Bs[(16 + (lane & 15)) * 32 + kq8];
        short8 b2 = *(const short8*)&Bs[(32 + (lane & 15)) * 32 + kq8];
        short8 b3 = *(const short8*)&Bs[(48 + (lane & 15)) * 32 + kq8];
        acc0 = __builtin_amdgcn_mfma_f32_16x16x32_bf16(af, b0, acc0, 0, 0, 0);
        acc1 = __builtin_amdgcn_mfma_f32_16x16x32_bf16(af, b1, acc1, 0, 0, 0);
        acc2 = __builtin_amdgcn_mfma_f32_16x16x32_bf16(af, b2, acc2, 0, 0, 0);
        acc3 = __builtin_amdgcn_mfma_f32_16x16x32_bf16(af, b3, acc3, 0, 0, 0);
    }

    // C/D layout (verified m89/m91): col = lane&15, row = (lane>>4)*4 + reg.
    floatx4 accs[4] = {acc0, acc1, acc2, acc3};
    int rbase = bm + wave * 16 + (lane >> 4) * 4;
    int cbase = bn + (lane & 15);
    #pragma unroll
    for (int gi = 0; gi < 4; ++gi) {
        int col = cbase + gi * 16;
        float bcol = bias[col];
        #pragma unroll
        for (int r = 0; r < 4; ++r) {
            int row = rbase + r;
            if (row >= M) continue;
            float val = accs[gi][r] + bcol;
            if (EP == 0) {
                int which = col / HS;
                int hd = col - which * HS;
                int head = hd >> 6, d = hd & 63;
                int lwin = row / TOK, tok = row - lwin * TOK;
                size_t idx = ((size_t)((lwin * NHEADS + head) * TOK + tok)) * HD + d;
                __hip_bfloat16* dst = (which == 0) ? oq : ((which == 1) ? okk : ov);
                dst[idx] = __float2bfloat16(val);
            } else if (EP == 1) {
                int lwin = row / TOK, tok = row - lwin * TOK;
                int win = win_base + lwin;
                int bb = win / WIN_PER_B, rr = win - bb * WIN_PER_B;
                int wi = rr / NSIDE, wj = rr - wi * NSIDE;
                int ti = tok / WSZ, tj = tok - ti * WSZ;
                int h = wi * WSZ + ti, w = wj * WSZ + tj;
                if (h < HWDIM && w < HWDIM) {
                    size_t idx = ((size_t)((bb * HWDIM + h) * HWDIM + w)) * HS + col;
                    of[idx] = resid[idx] + val;
                }
            } else if (EP == 2) {
                float ge = 0.5f * val * (1.0f + erff(val * 0.70710678118654752f));
                oh[(size_t)row * N + col] = __float2bfloat16(ge);
            } else {
                size_t idx = ((size_t)(m_base + row)) * HS + col;
                of[idx] += val;
            }
        }
    }
}

// ---- Attention, one block per (local window, head). 25*12=300 blocks/chunk.
// S kept in LDS fp32 for 49-row groups (4 groups of 196 rows): 49*197*4 = 38.6KB.
// 4 threads cooperate per query row (49-j strips + __shfl_xor softmax combine).
__global__ __launch_bounds__(256)
void attn_k(const __hip_bfloat16* __restrict__ qb, const __hip_bfloat16* __restrict__ kb,
            const __hip_bfloat16* __restrict__ vb,
            const float* __restrict__ rph, const float* __restrict__ rpw,
            __hip_bfloat16* __restrict__ ao)
{
    __shared__ float S[49 * 197];
    __shared__ float rel[49 * 28];   // per row: rh[0..13], rw[14..27]

    int bid = blockIdx.x;
    int lwin = bid / NHEADS, head = bid - lwin * NHEADS;
    size_t base = (size_t)(lwin * NHEADS + head) * TOK * HD;
    const unsigned short* q = (const unsigned short*)qb + base;
    const unsigned short* k = (const unsigned short*)kb + base;
    const unsigned short* v = (const unsigned short*)vb + base;

    int tid = threadIdx.x;
    bool act = tid < 196;
    int il = tid >> 2, part = tid & 3;

    for (int g = 0; g < 4; ++g) {
        int i0 = g * 49;
        float qr[HD];
        int ti = 0, tj = 0;
        if (act) {
            int i = i0 + il;
            ti = i / WSZ; tj = i - ti * WSZ;
            const uint4* q4 = (const uint4*)(q + (size_t)i * HD);
            #pragma unroll
            for (int c = 0; c < 8; ++c) {
                uint4 u = q4[c];
                const unsigned short* us = (const unsigned short*)&u;
                #pragma unroll
                for (int e = 0; e < 8; ++e) qr[c * 8 + e] = bf2f(us[e]);
            }
            // decomposed rel-pos bias dot products, split across the 4 parts
            int kk0 = (part & 1) * 7;
            bool isw = part >= 2;
            for (int kk = kk0; kk < kk0 + 7; ++kk) {
                const float* R = isw ? (rpw + (size_t)(tj - kk + WSZ - 1) * HD)
                                     : (rph + (size_t)(ti - kk + WSZ - 1) * HD);
                float acc = 0.f;
                #pragma unroll
                for (int d = 0; d < HD; ++d) acc += qr[d] * R[d];
                rel[il * 28 + (isw ? 14 : 0) + kk] = acc;
            }
        }
        __syncthreads();
        if (act) {
            int j0 = part * 49;
            int ki = j0 / WSZ, kj = j0 - ki * WSZ;
            for (int j = j0; j < j0 + 49; ++j) {
                const uint4* k4 = (const uint4*)(k + (size_t)j * HD);
                float dot = 0.f;
                #pragma unroll
                for (int c = 0; c < 8; ++c) {
                    uint4 u = k4[c];
                    const unsigned short* us = (const unsigned short*)&u;
                    #pragma unroll
                    for (int e = 0; e < 8; ++e) dot += qr[c * 8 + e] * bf2f(us[e]);
                }
                S[il * 197 + j] = dot * 0.125f + rel[il * 28 + ki] + rel[il * 28 + 14 + kj];
                if (++kj == WSZ) { kj = 0; ++ki; }
            }
            // softmax over the full row; 4 strip-threads combine via quad shfl
            float mx = -1e30f;
            for (int j = j0; j < j0 + 49; ++j) mx = fmaxf(mx, S[il * 197 + j]);
            mx = fmaxf(mx, __shfl_xor(mx, 1, 64));
            mx = fmaxf(mx, __shfl_xor(mx, 2, 64));
            float sum = 0.f;
            for (int j = j0; j < j0 + 49; ++j) {
                float e = __expf(S[il * 197 + j] - mx);
                S[il * 197 + j] = e;
                sum += e;
            }
            sum += __shfl_xor(sum, 1, 64);
            sum += __shfl_xor(sum, 2, 64);
            float inv = 1.0f / sum;
            for (int j = j0; j < j0 + 49; ++j) S[il * 197 + j] *= inv;
        }
        __syncthreads();
        // O = P @ V for this group's 49 rows; lanes of a wave share a row
        for (int o = tid; o < 49 * 64; o += 256) {
            int irow = o >> 6, d = o & 63;
            float acc = 0.f;
            for (int j = 0; j < TOK; ++j)
                acc += S[irow * 197 + j] * bf2f(v[(size_t)j * HD + d]);
            int i = i0 + irow;
            ao[((size_t)(lwin * TOK + i)) * HS + head * HD + d] = __float2bfloat16(acc);
        }
        __syncthreads();
    }
}

extern "C" void kernel_launch(void* const* d_in, const int* in_sizes, int n_in,
                              void* d_out, int out_size, void* d_ws, size_t ws_size,
                              hipStream_t stream)
{
    const float* x      = (const float*)d_in[0];
    const float* ln1_g  = (const float*)d_in[1];
    const float* ln1_b  = (const float*)d_in[2];
    const float* qkv_w  = (const float*)d_in[3];
    const float* qkv_b  = (const float*)d_in[4];
    const float* proj_w = (const float*)d_in[5];
    const float* proj_b = (const float*)d_in[6];
    const float* rph    = (const float*)d_in[7];
    const float* rpw    = (const float*)d_in[8];
    const float* ln2_g  = (const float*)d_in[9];
    const float* ln2_b  = (const float*)d_in[10];
    const float* mlp_w1 = (const float*)d_in[11];
    const float* mlp_b1 = (const float*)d_in[12];
    const float* mlp_w2 = (const float*)d_in[13];
    const float* mlp_b2 = (const float*)d_in[14];
    float* out = (float*)d_out;

    char* ws = (char*)d_ws;
    // workspace layout (all offsets 256B-aligned), total ~114.8 MB
    __hip_bfloat16* wqkv  = (__hip_bfloat16*)(ws + 0);          // [2304][768]
    __hip_bfloat16* wproj = (__hip_bfloat16*)(ws + 3538944);    // [768][768]
    __hip_bfloat16* wm1   = (__hip_bfloat16*)(ws + 4718592);    // [3072][768]
    __hip_bfloat16* wm2   = (__hip_bfloat16*)(ws + 9437184);    // [768][3072]
    __hip_bfloat16* ybuf  = (__hip_bfloat16*)(ws + 14155776);   // 32768x768 (y, then ln2 out)
    char* R2 = ws + 64487424;                                   // 50,331,648 B region
    __hip_bfloat16* qc  = (__hip_bfloat16*)(R2);                // chunk q  [25*12*196*64]
    __hip_bfloat16* kc  = (__hip_bfloat16*)(R2 + 7526400);      // chunk k
    __hip_bfloat16* vc  = (__hip_bfloat16*)(R2 + 15052800);     // chunk v
    __hip_bfloat16* ao  = (__hip_bfloat16*)(R2 + 22579200);     // chunk attn out [4900][768]
    __hip_bfloat16* hid = (__hip_bfloat16*)(R2);                // mlp hidden [8192][3072]

    // weights -> bf16, transposed to [N][K]
    cvt_t_k<<<dim3(6912), 256, 0, stream>>>(qkv_w,  wqkv,  768, 2304);
    cvt_t_k<<<dim3(2304), 256, 0, stream>>>(proj_w, wproj, 768, 768);
    cvt_t_k<<<dim3(9216), 256, 0, stream>>>(mlp_w1, wm1,   768, 3072);
    cvt_t_k<<<dim3(9216), 256, 0, stream>>>(mlp_w2, wm2,  3072, 768);

    // LN1 -> y (bf16, natural token layout; window gather happens in qkv staging)
    ln_k<<<dim3(32768), 256, 0, stream>>>(x, ln1_g, ln1_b, ybuf);

    // windowed attention, 8 chunks of 25 windows (= 1 batch image each)
    for (int wc = 0; wc < 8; ++wc) {
        gemm_k<0, 1><<<dim3(77, 36), 256, 0, stream>>>(
            ybuf, wqkv, qkv_b, MCH, 2304, 768,
            qc, kc, vc, nullptr, nullptr, nullptr, wc * WCHUNK, 0);
        attn_k<<<dim3(300), 256, 0, stream>>>(qc, kc, vc, rph, rpw, ao);
        gemm_k<1, 0><<<dim3(77, 12), 256, 0, stream>>>(
            ao, wproj, proj_b, MCH, 768, 768,
            nullptr, nullptr, nullptr, out, x, nullptr, wc * WCHUNK, 0);
    }

    // LN2 over attention residual -> bf16
    ln_k<<<dim3(32768), 256, 0, stream>>>(out, ln2_g, ln2_b, ybuf);

    // MLP in 4 token chunks (hidden reuses R2)
    for (int mc = 0; mc < 4; ++mc) {
        gemm_k<2, 0><<<dim3(128, 48), 256, 0, stream>>>(
            ybuf + (size_t)mc * MLPCH * HS, wm1, mlp_b1, MLPCH, 3072, 768,
            nullptr, nullptr, nullptr, nullptr, nullptr, hid, 0, 0);
        gemm_k<3, 0><<<dim3(128, 12), 256, 0, stream>>>(
            hid, wm2, mlp_b2, MLPCH, 768, 3072,
            nullptr, nullptr, nullptr, out, nullptr, nullptr, 0, mc * MLPCH);
    }
}

// Round 2
// 2639.585 us; speedup vs baseline: 2.3804x; 2.3804x over previous
//
#include <hip/hip_runtime.h>
#include <hip/hip_bf16.h>
#include <math.h>

// SAM vision layer: LN1 -> windowed attention (decomposed rel-pos bias) -> proj
// + residual -> LN2 -> MLP(GELU exact) -> residual.
// B=8, H=W=64, HS=768, NH=12, HD=64, WS=14 -> 200 windows x 196 tokens.

#define HS 768
#define NHEADS 12
#define HD 64
#define WSZ 14
#define TOK 196
#define HWDIM 64
#define NSIDE 5
#define WIN_PER_B 25
#define WCHUNK 25
#define MCH 4900        // rows per window chunk = 25*196
#define MLPCH 8192      // tokens per MLP chunk (32768/4)

typedef __attribute__((ext_vector_type(8))) short short8;
typedef __attribute__((ext_vector_type(4))) float floatx4;

__device__ __forceinline__ float bf2f(unsigned short u) {
    union { unsigned int i; float f; } w; w.i = ((unsigned int)u) << 16; return w.f;
}
__device__ __forceinline__ unsigned short f2bu(float f) {
    __hip_bfloat16 h = __float2bfloat16(f);
    return *(unsigned short*)&h;
}

// ---- fp32 -> bf16 transposed convert: src[K][N] -> dst[N][K] ----
__global__ __launch_bounds__(256)
void cvt_t_k(const float* __restrict__ src, __hip_bfloat16* __restrict__ dst,
             int K, int N) {
    int idx = blockIdx.x * 256 + threadIdx.x;
    if (idx >= K * N) return;
    int k = idx / N, n = idx - k * N;
    dst[(size_t)n * K + k] = __float2bfloat16(src[idx]);
}

// ---- LayerNorm over HS=768, one block per row, 256 threads (3 elems each) ----
__global__ __launch_bounds__(256)
void ln_k(const float* __restrict__ x, const float* __restrict__ g,
          const float* __restrict__ b, __hip_bfloat16* __restrict__ y) {
    int row = blockIdx.x;
    const float* xr = x + (size_t)row * HS;
    int tid = threadIdx.x;
    float v0 = xr[tid], v1 = xr[tid + 256], v2 = xr[tid + 512];
    float s = v0 + v1 + v2;
    float q = v0 * v0 + v1 * v1 + v2 * v2;
    for (int off = 32; off > 0; off >>= 1) {
        s += __shfl_down(s, off, 64);
        q += __shfl_down(q, off, 64);
    }
    __shared__ float ss[4], sq[4];
    int wave = tid >> 6, lane = tid & 63;
    if (lane == 0) { ss[wave] = s; sq[wave] = q; }
    __syncthreads();
    if (tid == 0) {
        float S = ss[0] + ss[1] + ss[2] + ss[3];
        float Q = sq[0] + sq[1] + sq[2] + sq[3];
        float mu = S * (1.0f / HS);
        float var = Q * (1.0f / HS) - mu * mu;
        ss[0] = mu;
        sq[0] = rsqrtf(var + 1e-6f);
    }
    __syncthreads();
    float mu = ss[0], rstd = sq[0];
    __hip_bfloat16* yr = y + (size_t)row * HS;
    yr[tid]       = __float2bfloat16((v0 - mu) * rstd * g[tid]       + b[tid]);
    yr[tid + 256] = __float2bfloat16((v1 - mu) * rstd * g[tid + 256] + b[tid + 256]);
    yr[tid + 512] = __float2bfloat16((v2 - mu) * rstd * g[tid + 512] + b[tid + 512]);
}

// ---- Generic bf16 MFMA GEMM, 64x64 tile, 4 waves (each: 16 rows x 64 cols).
template<int EP, int AGATHER>
__global__ __launch_bounds__(256)
void gemm_k(const __hip_bfloat16* __restrict__ A,
            const __hip_bfloat16* __restrict__ Bt,
            const float* __restrict__ bias,
            int M, int N, int K,
            __hip_bfloat16* __restrict__ oq, __hip_bfloat16* __restrict__ okk,
            __hip_bfloat16* __restrict__ ov,
            float* __restrict__ of, const float* __restrict__ resid,
            __hip_bfloat16* __restrict__ oh,
            int win_base, int m_base)
{
    __shared__ unsigned short As[64 * 32];
    __shared__ unsigned short Bs[64 * 32];
    __shared__ int rowsrc[64];

    int tid = threadIdx.x;
    int bm = blockIdx.x * 64;
    int bn = blockIdx.y * 64;
    int wave = tid >> 6, lane = tid & 63;

    if (tid < 64) {
        int m = bm + tid;
        int src = -1;
        if (m < M) {
            if (AGATHER) {
                int lwin = m / TOK, tok = m - lwin * TOK;
                int win = win_base + lwin;
                int bb = win / WIN_PER_B, r = win - bb * WIN_PER_B;
                int wi = r / NSIDE, wj = r - wi * NSIDE;
                int ti = tok / WSZ, tj = tok - ti * WSZ;
                int h = wi * WSZ + ti, w = wj * WSZ + tj;
                if (h < HWDIM && w < HWDIM) src = (bb * HWDIM + h) * HWDIM + w;
            } else {
                src = m;
            }
        }
        rowsrc[tid] = src;
    }
    __syncthreads();

    int smm = tid >> 2;
    int sk8 = (tid & 3) * 8;
    int asrc = rowsrc[smm];
    const unsigned short* Au = (const unsigned short*)A;
    const unsigned short* Bu = (const unsigned short*)Bt;

    floatx4 acc0 = {0.f, 0.f, 0.f, 0.f}, acc1 = acc0, acc2 = acc0, acc3 = acc0;

    int arow = wave * 16 + (lane & 15);
    int kq8 = (lane >> 4) * 8;

    for (int k0 = 0; k0 < K; k0 += 32) {
        uint4 av = {0u, 0u, 0u, 0u};
        if (asrc >= 0) av = *(const uint4*)(Au + (size_t)asrc * K + k0 + sk8);
        uint4 bv = *(const uint4*)(Bu + (size_t)(bn + smm) * K + k0 + sk8);
        __syncthreads();
        *(uint4*)&As[smm * 32 + sk8] = av;
        *(uint4*)&Bs[smm * 32 + sk8] = bv;
        __syncthreads();
        short8 af = *(const short8*)&As[arow * 32 + kq8];
        short8 b0 = *(const short8*)&Bs[( 0 + (lane & 15)) * 32 + kq8];
        short8 b1 = *(const short8*)&Bs[(16 + (lane & 15)) * 32 + kq8];
        short8 b2 = *(const short8*)&Bs[(32 + (lane & 15)) * 32 + kq8];
        short8 b3 = *(const short8*)&Bs[(48 + (lane & 15)) * 32 + kq8];
        acc0 = __builtin_amdgcn_mfma_f32_16x16x32_bf16(af, b0, acc0, 0, 0, 0);
        acc1 = __builtin_amdgcn_mfma_f32_16x16x32_bf16(af, b1, acc1, 0, 0, 0);
        acc2 = __builtin_amdgcn_mfma_f32_16x16x32_bf16(af, b2, acc2, 0, 0, 0);
        acc3 = __builtin_amdgcn_mfma_f32_16x16x32_bf16(af, b3, acc3, 0, 0, 0);
    }

    floatx4 accs[4] = {acc0, acc1, acc2, acc3};
    int rbase = bm + wave * 16 + (lane >> 4) * 4;
    int cbase = bn + (lane & 15);
    #pragma unroll
    for (int gi = 0; gi < 4; ++gi) {
        int col = cbase + gi * 16;
        float bcol = bias[col];
        #pragma unroll
        for (int r = 0; r < 4; ++r) {
            int row = rbase + r;
            if (row >= M) continue;
            float val = accs[gi][r] + bcol;
            if (EP == 0) {
                int which = col / HS;
                int hd = col - which * HS;
                int head = hd >> 6, d = hd & 63;
                int lwin = row / TOK, tok = row - lwin * TOK;
                size_t idx = ((size_t)((lwin * NHEADS + head) * TOK + tok)) * HD + d;
                __hip_bfloat16* dst = (which == 0) ? oq : ((which == 1) ? okk : ov);
                dst[idx] = __float2bfloat16(val);
            } else if (EP == 1) {
                int lwin = row / TOK, tok = row - lwin * TOK;
                int win = win_base + lwin;
                int bb = win / WIN_PER_B, rr = win - bb * WIN_PER_B;
                int wi = rr / NSIDE, wj = rr - wi * NSIDE;
                int ti = tok / WSZ, tj = tok - ti * WSZ;
                int h = wi * WSZ + ti, w = wj * WSZ + tj;
                if (h < HWDIM && w < HWDIM) {
                    size_t idx = ((size_t)((bb * HWDIM + h) * HWDIM + w)) * HS + col;
                    of[idx] = resid[idx] + val;
                }
            } else if (EP == 2) {
                float ge = 0.5f * val * (1.0f + erff(val * 0.70710678118654752f));
                oh[(size_t)row * N + col] = __float2bfloat16(ge);
            } else {
                size_t idx = ((size_t)(m_base + row)) * HS + col;
                of[idx] += val;
            }
        }
    }
}

// ---- MFMA attention. One block per (local window, head); 4 waves.
// Wave w owns q-tiles {w, w+4, w+8, w+12} of the 13 16-row tiles (196 rows).
// K staged [208][72] bf16 in LDS (b128-aligned, 2-way banks); V staged
// transposed [64][232]; per-wave 1280B scratch (rel bias, then P fragments).
__global__ __launch_bounds__(256)
void attn_k(const __hip_bfloat16* __restrict__ qb, const __hip_bfloat16* __restrict__ kb,
            const __hip_bfloat16* __restrict__ vb,
            const float* __restrict__ rph, const float* __restrict__ rpw,
            __hip_bfloat16* __restrict__ ao)
{
    __shared__ unsigned short Ks[208 * 72];   // 29952 B
    __shared__ unsigned short Vt[64 * 232];   // 29696 B
    __shared__ unsigned short scr[4 * 640];   // 5120 B (per-wave 1280 B)

    int bid = blockIdx.x;
    int lwin = bid / NHEADS, head = bid - lwin * NHEADS;
    size_t base = (size_t)(lwin * NHEADS + head) * TOK * HD;
    const unsigned short* q = (const unsigned short*)qb + base;
    const unsigned short* k = (const unsigned short*)kb + base;
    const unsigned short* v = (const unsigned short*)vb + base;

    int tid = threadIdx.x;
    int wave = tid >> 6, lane = tid & 63;
    int n16 = lane & 15, quad = lane >> 4;

    // ---- stage K: 196 rows x 64 bf16 (uint4 chunks) ----
    for (int idx = tid; idx < 1568; idx += 256) {
        int row = idx >> 3, q8 = (idx & 7) << 3;
        *(uint4*)&Ks[row * 72 + q8] = *(const uint4*)(k + (size_t)row * HD + q8);
    }
    if (tid < 96) {  // zero pad rows 196..207
        int row = 196 + (tid >> 3), q8 = (tid & 7) << 3;
        uint4 z = {0u, 0u, 0u, 0u};
        *(uint4*)&Ks[row * 72 + q8] = z;
    }
    // ---- stage V transposed: Vt[d][tok], 4 toks packed per write ----
    for (int s = tid; s < 49 * 64; s += 256) {
        int g = s >> 6, d = s & 63;             // toks 4g..4g+3, dim d
        unsigned int w0 = ((unsigned int)v[(size_t)(4 * g + 0) * HD + d]) |
                          ((unsigned int)v[(size_t)(4 * g + 1) * HD + d] << 16);
        unsigned int w1 = ((unsigned int)v[(size_t)(4 * g + 2) * HD + d]) |
                          ((unsigned int)v[(size_t)(4 * g + 3) * HD + d] << 16);
        uint2 pk = {w0, w1};
        *(uint2*)&Vt[d * 232 + 4 * g] = pk;
    }
    for (int s = tid; s < 512; s += 256) {      // zero pad cols 196..227
        int r = s >> 3, c = 196 + ((s & 7) << 2);
        uint2 z = {0u, 0u};
        *(uint2*)&Vt[r * 232 + c] = z;
    }
    __syncthreads();

    unsigned short* myscr = &scr[wave * 640];
    int rl0 = quad * 4;                          // local row base within q-tile

    for (int qt = wave; qt < 13; qt += 4) {
        int qrow = qt * 16 + n16;
        int qr = qrow < 196 ? qrow : 195;
        bool qvalid = qrow < 196;

        // Q A-fragments (k 0..31 and 32..63)
        short8 qf0 = {0, 0, 0, 0, 0, 0, 0, 0}, qf1 = qf0;
        if (qvalid) {
            qf0 = *(const short8*)(q + (size_t)qr * HD + quad * 8);
            qf1 = *(const short8*)(q + (size_t)qr * HD + 32 + quad * 8);
        }

        // rel-pos bias: lane computes 7 dots (row = n16's qr, c = quad+4*it)
        {
            float qv[64];
            const uint4* q4 = (const uint4*)(q + (size_t)qr * HD);
            #pragma unroll
            for (int c8 = 0; c8 < 8; ++c8) {
                uint4 u = q4[c8];
                const unsigned short* us = (const unsigned short*)&u;
                #pragma unroll
                for (int e = 0; e < 8; ++e) qv[c8 * 8 + e] = bf2f(us[e]);
            }
            int ti = qr / WSZ, tj = qr - ti * WSZ;
            #pragma unroll
            for (int it = 0; it < 7; ++it) {
                int c = quad + 4 * it;           // 0..27
                const float* R = (c < WSZ) ? (rph + (size_t)(ti - c + WSZ - 1) * HD)
                                           : (rpw + (size_t)(tj - (c - WSZ) + WSZ - 1) * HD);
                const float4* R4 = (const float4*)R;
                float acc = 0.f;
                #pragma unroll
                for (int d4 = 0; d4 < 16; ++d4) {
                    float4 rv = R4[d4];
                    acc += qv[4 * d4] * rv.x + qv[4 * d4 + 1] * rv.y +
                           qv[4 * d4 + 2] * rv.z + qv[4 * d4 + 3] * rv.w;
                }
                myscr[n16 * 32 + c] = f2bu(acc);
            }
        }

        // S = Q K^T (13 n-tiles in registers)
        floatx4 S[13];
        #pragma unroll
        for (int nt = 0; nt < 13; ++nt) {
            short8 kf0 = *(const short8*)&Ks[(nt * 16 + n16) * 72 + quad * 8];
            short8 kf1 = *(const short8*)&Ks[(nt * 16 + n16) * 72 + 32 + quad * 8];
            floatx4 a = {0.f, 0.f, 0.f, 0.f};
            a = __builtin_amdgcn_mfma_f32_16x16x32_bf16(qf0, kf0, a, 0, 0, 0);
            a = __builtin_amdgcn_mfma_f32_16x16x32_bf16(qf1, kf1, a, 0, 0, 0);
            S[nt] = a;
        }

        // scale + rel bias + mask pad cols
        #pragma unroll
        for (int nt = 0; nt < 13; ++nt) {
            int col = nt * 16 + n16;
            int ki = col / WSZ, kj = col - ki * WSZ;
            #pragma unroll
            for (int r = 0; r < 4; ++r) {
                float rh = bf2f(myscr[(rl0 + r) * 32 + ki]);
                float rw = bf2f(myscr[(rl0 + r) * 32 + WSZ + kj]);
                S[nt][r] = S[nt][r] * 0.125f + rh + rw;
            }
            if (nt == 12) {
                if (n16 >= 4) {
                    #pragma unroll
                    for (int r = 0; r < 4; ++r) S[12][r] = -1e30f;
                }
            }
        }

        // row softmax (rows spread over 16 lanes of the quad-group + 13 tiles)
        float mxr[4] = {-3e30f, -3e30f, -3e30f, -3e30f};
        #pragma unroll
        for (int nt = 0; nt < 13; ++nt)
            #pragma unroll
            for (int r = 0; r < 4; ++r) mxr[r] = fmaxf(mxr[r], S[nt][r]);
        #pragma unroll
        for (int m = 1; m <= 8; m <<= 1)
            #pragma unroll
            for (int r = 0; r < 4; ++r) mxr[r] = fmaxf(mxr[r], __shfl_xor(mxr[r], m, 64));
        float sum[4] = {0.f, 0.f, 0.f, 0.f};
        #pragma unroll
        for (int nt = 0; nt < 13; ++nt)
            #pragma unroll
            for (int r = 0; r < 4; ++r) {
                float e = __expf(S[nt][r] - mxr[r]);
                S[nt][r] = e;
                sum[r] += e;
            }
        #pragma unroll
        for (int m = 1; m <= 8; m <<= 1)
            #pragma unroll
            for (int r = 0; r < 4; ++r) sum[r] += __shfl_xor(sum[r], m, 64);
        float inv[4];
        #pragma unroll
        for (int r = 0; r < 4; ++r) inv[r] = 1.0f / sum[r];

        // O = P V  (P round-trips through per-wave scratch into A-layout)
        floatx4 O[4] = {{0.f,0.f,0.f,0.f},{0.f,0.f,0.f,0.f},{0.f,0.f,0.f,0.f},{0.f,0.f,0.f,0.f}};
        #pragma unroll
        for (int ks = 0; ks < 7; ++ks) {
            #pragma unroll
            for (int r = 0; r < 4; ++r) {
                myscr[(rl0 + r) * 40 + n16] = f2bu(S[2 * ks][r] * inv[r]);
                myscr[(rl0 + r) * 40 + 16 + n16] =
                    (2 * ks + 1 < 13) ? f2bu(S[2 * ks + 1][r] * inv[r]) : (unsigned short)0;
            }
            short8 pf = *(const short8*)&myscr[n16 * 40 + quad * 8];
            #pragma unroll
            for (int nt4 = 0; nt4 < 4; ++nt4) {
                short8 vf = *(const short8*)&Vt[(nt4 * 16 + n16) * 232 + ks * 32 + quad * 8];
                O[nt4] = __builtin_amdgcn_mfma_f32_16x16x32_bf16(pf, vf, O[nt4], 0, 0, 0);
            }
        }

        // store O tile (rows quad*4+r, cols d = nt4*16+n16)
        #pragma unroll
        for (int nt4 = 0; nt4 < 4; ++nt4) {
            int d = nt4 * 16 + n16;
            #pragma unroll
            for (int r = 0; r < 4; ++r) {
                int row = qt * 16 + rl0 + r;
                if (row < 196) {
                    ao[((size_t)(lwin * TOK + row)) * HS + head * HD + d] =
                        __float2bfloat16(O[nt4][r]);
                }
            }
        }
    }
}

extern "C" void kernel_launch(void* const* d_in, const int* in_sizes, int n_in,
                              void* d_out, int out_size, void* d_ws, size_t ws_size,
                              hipStream_t stream)
{
    const float* x      = (const float*)d_in[0];
    const float* ln1_g  = (const float*)d_in[1];
    const float* ln1_b  = (const float*)d_in[2];
    const float* qkv_w  = (const float*)d_in[3];
    const float* qkv_b  = (const float*)d_in[4];
    const float* proj_w = (const float*)d_in[5];
    const float* proj_b = (const float*)d_in[6];
    const float* rph    = (const float*)d_in[7];
    const float* rpw    = (const float*)d_in[8];
    const float* ln2_g  = (const float*)d_in[9];
    const float* ln2_b  = (const float*)d_in[10];
    const float* mlp_w1 = (const float*)d_in[11];
    const float* mlp_b1 = (const float*)d_in[12];
    const float* mlp_w2 = (const float*)d_in[13];
    const float* mlp_b2 = (const float*)d_in[14];
    float* out = (float*)d_out;

    char* ws = (char*)d_ws;
    __hip_bfloat16* wqkv  = (__hip_bfloat16*)(ws + 0);          // [2304][768]
    __hip_bfloat16* wproj = (__hip_bfloat16*)(ws + 3538944);    // [768][768]
    __hip_bfloat16* wm1   = (__hip_bfloat16*)(ws + 4718592);    // [3072][768]
    __hip_bfloat16* wm2   = (__hip_bfloat16*)(ws + 9437184);    // [768][3072]
    __hip_bfloat16* ybuf  = (__hip_bfloat16*)(ws + 14155776);   // 32768x768
    char* R2 = ws + 64487424;
    __hip_bfloat16* qc  = (__hip_bfloat16*)(R2);
    __hip_bfloat16* kc  = (__hip_bfloat16*)(R2 + 7526400);
    __hip_bfloat16* vc  = (__hip_bfloat16*)(R2 + 15052800);
    __hip_bfloat16* ao  = (__hip_bfloat16*)(R2 + 22579200);
    __hip_bfloat16* hid = (__hip_bfloat16*)(R2);

    cvt_t_k<<<dim3(6912), 256, 0, stream>>>(qkv_w,  wqkv,  768, 2304);
    cvt_t_k<<<dim3(2304), 256, 0, stream>>>(proj_w, wproj, 768, 768);
    cvt_t_k<<<dim3(9216), 256, 0, stream>>>(mlp_w1, wm1,   768, 3072);
    cvt_t_k<<<dim3(9216), 256, 0, stream>>>(mlp_w2, wm2,  3072, 768);

    ln_k<<<dim3(32768), 256, 0, stream>>>(x, ln1_g, ln1_b, ybuf);

    for (int wc = 0; wc < 8; ++wc) {
        gemm_k<0, 1><<<dim3(77, 36), 256, 0, stream>>>(
            ybuf, wqkv, qkv_b, MCH, 2304, 768,
            qc, kc, vc, nullptr, nullptr, nullptr, wc * WCHUNK, 0);
        attn_k<<<dim3(300), 256, 0, stream>>>(qc, kc, vc, rph, rpw, ao);
        gemm_k<1, 0><<<dim3(77, 12), 256, 0, stream>>>(
            ao, wproj, proj_b, MCH, 768, 768,
            nullptr, nullptr, nullptr, out, x, nullptr, wc * WCHUNK, 0);
    }

    ln_k<<<dim3(32768), 256, 0, stream>>>(out, ln2_g, ln2_b, ybuf);

    for (int mc = 0; mc < 4; ++mc) {
        gemm_k<2, 0><<<dim3(128, 48), 256, 0, stream>>>(
            ybuf + (size_t)mc * MLPCH * HS, wm1, mlp_b1, MLPCH, 3072, 768,
            nullptr, nullptr, nullptr, nullptr, nullptr, hid, 0, 0);
        gemm_k<3, 0><<<dim3(128, 12), 256, 0, stream>>>(
            hid, wm2, mlp_b2, MLPCH, 768, 3072,
            nullptr, nullptr, nullptr, out, nullptr, nullptr, 0, mc * MLPCH);
    }
}

// Round 3
// 2073.726 us; speedup vs baseline: 3.0299x; 1.2729x over previous
//
#include <hip/hip_runtime.h>
#include <hip/hip_bf16.h>
#include <math.h>

// SAM vision layer: LN1 -> windowed attention (decomposed rel-pos bias) -> proj
// + residual -> LN2 -> MLP(GELU exact) -> residual.
// B=8, H=W=64, HS=768, NH=12, HD=64, WS=14 -> 200 windows x 196 tokens.

#define HS 768
#define NHEADS 12
#define HD 64
#define WSZ 14
#define TOK 196
#define HWDIM 64
#define NSIDE 5
#define WIN_PER_B 25
#define WCHUNK 25
#define MCH 4900        // rows per window chunk = 25*196
#define MLPCH 8192      // tokens per MLP chunk (32768/4)

typedef __attribute__((ext_vector_type(8))) short short8;
typedef __attribute__((ext_vector_type(4))) float floatx4;

__device__ __forceinline__ float bf2f(unsigned short u) {
    union { unsigned int i; float f; } w; w.i = ((unsigned int)u) << 16; return w.f;
}
__device__ __forceinline__ unsigned short f2bu(float f) {
    __hip_bfloat16 h = __float2bfloat16(f);
    return *(unsigned short*)&h;
}

// ---- fp32 -> bf16 transposed convert: src[K][N] -> dst[N][K] ----
__global__ __launch_bounds__(256)
void cvt_t_k(const float* __restrict__ src, __hip_bfloat16* __restrict__ dst,
             int K, int N) {
    int idx = blockIdx.x * 256 + threadIdx.x;
    if (idx >= K * N) return;
    int k = idx / N, n = idx - k * N;
    dst[(size_t)n * K + k] = __float2bfloat16(src[idx]);
}

// ---- LayerNorm over HS=768, one block per row, 256 threads (3 elems each) ----
__global__ __launch_bounds__(256)
void ln_k(const float* __restrict__ x, const float* __restrict__ g,
          const float* __restrict__ b, __hip_bfloat16* __restrict__ y) {
    int row = blockIdx.x;
    const float* xr = x + (size_t)row * HS;
    int tid = threadIdx.x;
    float v0 = xr[tid], v1 = xr[tid + 256], v2 = xr[tid + 512];
    float s = v0 + v1 + v2;
    float q = v0 * v0 + v1 * v1 + v2 * v2;
    for (int off = 32; off > 0; off >>= 1) {
        s += __shfl_down(s, off, 64);
        q += __shfl_down(q, off, 64);
    }
    __shared__ float ss[4], sq[4];
    int wave = tid >> 6, lane = tid & 63;
    if (lane == 0) { ss[wave] = s; sq[wave] = q; }
    __syncthreads();
    if (tid == 0) {
        float S = ss[0] + ss[1] + ss[2] + ss[3];
        float Q = sq[0] + sq[1] + sq[2] + sq[3];
        float mu = S * (1.0f / HS);
        float var = Q * (1.0f / HS) - mu * mu;
        ss[0] = mu;
        sq[0] = rsqrtf(var + 1e-6f);
    }
    __syncthreads();
    float mu = ss[0], rstd = sq[0];
    __hip_bfloat16* yr = y + (size_t)row * HS;
    yr[tid]       = __float2bfloat16((v0 - mu) * rstd * g[tid]       + b[tid]);
    yr[tid + 256] = __float2bfloat16((v1 - mu) * rstd * g[tid + 256] + b[tid + 256]);
    yr[tid + 512] = __float2bfloat16((v2 - mu) * rstd * g[tid + 512] + b[tid + 512]);
}

// ---- Generic bf16 MFMA GEMM, 64x64 tile, 4 waves (each: 16 rows x 64 cols).
template<int EP, int AGATHER>
__global__ __launch_bounds__(256)
void gemm_k(const __hip_bfloat16* __restrict__ A,
            const __hip_bfloat16* __restrict__ Bt,
            const float* __restrict__ bias,
            int M, int N, int K,
            __hip_bfloat16* __restrict__ oq, __hip_bfloat16* __restrict__ okk,
            __hip_bfloat16* __restrict__ ov,
            float* __restrict__ of, const float* __restrict__ resid,
            __hip_bfloat16* __restrict__ oh,
            int win_base, int m_base)
{
    __shared__ unsigned short As[64 * 32];
    __shared__ unsigned short Bs[64 * 32];
    __shared__ int rowsrc[64];

    int tid = threadIdx.x;
    int bm = blockIdx.x * 64;
    int bn = blockIdx.y * 64;
    int wave = tid >> 6, lane = tid & 63;

    if (tid < 64) {
        int m = bm + tid;
        int src = -1;
        if (m < M) {
            if (AGATHER) {
                int lwin = m / TOK, tok = m - lwin * TOK;
                int win = win_base + lwin;
                int bb = win / WIN_PER_B, r = win - bb * WIN_PER_B;
                int wi = r / NSIDE, wj = r - wi * NSIDE;
                int ti = tok / WSZ, tj = tok - ti * WSZ;
                int h = wi * WSZ + ti, w = wj * WSZ + tj;
                if (h < HWDIM && w < HWDIM) src = (bb * HWDIM + h) * HWDIM + w;
            } else {
                src = m;
            }
        }
        rowsrc[tid] = src;
    }
    __syncthreads();

    int smm = tid >> 2;
    int sk8 = (tid & 3) * 8;
    int asrc = rowsrc[smm];
    const unsigned short* Au = (const unsigned short*)A;
    const unsigned short* Bu = (const unsigned short*)Bt;

    floatx4 acc0 = {0.f, 0.f, 0.f, 0.f}, acc1 = acc0, acc2 = acc0, acc3 = acc0;

    int arow = wave * 16 + (lane & 15);
    int kq8 = (lane >> 4) * 8;

    for (int k0 = 0; k0 < K; k0 += 32) {
        uint4 av = {0u, 0u, 0u, 0u};
        if (asrc >= 0) av = *(const uint4*)(Au + (size_t)asrc * K + k0 + sk8);
        uint4 bv = *(const uint4*)(Bu + (size_t)(bn + smm) * K + k0 + sk8);
        __syncthreads();
        *(uint4*)&As[smm * 32 + sk8] = av;
        *(uint4*)&Bs[smm * 32 + sk8] = bv;
        __syncthreads();
        short8 af = *(const short8*)&As[arow * 32 + kq8];
        short8 b0 = *(const short8*)&Bs[( 0 + (lane & 15)) * 32 + kq8];
        short8 b1 = *(const short8*)&Bs[(16 + (lane & 15)) * 32 + kq8];
        short8 b2 = *(const short8*)&Bs[(32 + (lane & 15)) * 32 + kq8];
        short8 b3 = *(const short8*)&Bs[(48 + (lane & 15)) * 32 + kq8];
        acc0 = __builtin_amdgcn_mfma_f32_16x16x32_bf16(af, b0, acc0, 0, 0, 0);
        acc1 = __builtin_amdgcn_mfma_f32_16x16x32_bf16(af, b1, acc1, 0, 0, 0);
        acc2 = __builtin_amdgcn_mfma_f32_16x16x32_bf16(af, b2, acc2, 0, 0, 0);
        acc3 = __builtin_amdgcn_mfma_f32_16x16x32_bf16(af, b3, acc3, 0, 0, 0);
    }

    floatx4 accs[4] = {acc0, acc1, acc2, acc3};
    int rbase = bm + wave * 16 + (lane >> 4) * 4;
    int cbase = bn + (lane & 15);
    #pragma unroll
    for (int gi = 0; gi < 4; ++gi) {
        int col = cbase + gi * 16;
        float bcol = bias[col];
        #pragma unroll
        for (int r = 0; r < 4; ++r) {
            int row = rbase + r;
            if (row >= M) continue;
            float val = accs[gi][r] + bcol;
            if (EP == 0) {
                int which = col / HS;
                int hd = col - which * HS;
                int head = hd >> 6, d = hd & 63;
                int lwin = row / TOK, tok = row - lwin * TOK;
                size_t idx = ((size_t)((lwin * NHEADS + head) * TOK + tok)) * HD + d;
                __hip_bfloat16* dst = (which == 0) ? oq : ((which == 1) ? okk : ov);
                dst[idx] = __float2bfloat16(val);
            } else if (EP == 1) {
                int lwin = row / TOK, tok = row - lwin * TOK;
                int win = win_base + lwin;
                int bb = win / WIN_PER_B, rr = win - bb * WIN_PER_B;
                int wi = rr / NSIDE, wj = rr - wi * NSIDE;
                int ti = tok / WSZ, tj = tok - ti * WSZ;
                int h = wi * WSZ + ti, w = wj * WSZ + tj;
                if (h < HWDIM && w < HWDIM) {
                    size_t idx = ((size_t)((bb * HWDIM + h) * HWDIM + w)) * HS + col;
                    of[idx] = resid[idx] + val;
                }
            } else if (EP == 2) {
                float ge = 0.5f * val * (1.0f + erff(val * 0.70710678118654752f));
                oh[(size_t)row * N + col] = __float2bfloat16(ge);
            } else {
                size_t idx = ((size_t)(m_base + row)) * HS + col;
                of[idx] += val;
            }
        }
    }
}

// ---- MFMA attention. One block per (local window, head); 4 waves.
// Rel-pos bias is ALSO MFMA: rel[i][c] = q_i . table[c], table = 54x64
// (27 rph rows at c=0..26, 27 rpw rows at c=27..53), B-fragments loop-invariant
// in registers. LDS (one combined array, 63808 B -> 2 blocks/CU):
//   Ks  [196][72] bf16 at 0      (reads for pad rows 196..207 overflow into Vt
//                                 region: finite bf16 garbage, masked in S)
//   Vt  [64][224] bf16 at 14112  (V transposed; cols 196..223 zeroed)
//   scr 4 x 864 shorts at 28448  (per-wave: rel result [16][54], then P [16][40])
__global__ __launch_bounds__(256)
void attn_k(const __hip_bfloat16* __restrict__ qb, const __hip_bfloat16* __restrict__ kb,
            const __hip_bfloat16* __restrict__ vb,
            const float* __restrict__ rph, const float* __restrict__ rpw,
            __hip_bfloat16* __restrict__ ao)
{
    __shared__ __align__(16) unsigned short lds[31904];
    unsigned short* Ks = lds;            // stride 72
    unsigned short* Vt = lds + 14112;    // stride 224
    unsigned short* scr = lds + 28448;   // 4 x 864

    int bid = blockIdx.x;
    int lwin = bid / NHEADS, head = bid - lwin * NHEADS;
    size_t base = (size_t)(lwin * NHEADS + head) * TOK * HD;
    const unsigned short* q = (const unsigned short*)qb + base;
    const unsigned short* k = (const unsigned short*)kb + base;
    const unsigned short* v = (const unsigned short*)vb + base;

    int tid = threadIdx.x;
    int wave = tid >> 6, lane = tid & 63;
    int n16 = lane & 15, quad = lane >> 4;

    // ---- loop-invariant rel-table B fragments (bf16 from fp32 tables) ----
    short8 btab[4][2];
    #pragma unroll
    for (int nt = 0; nt < 4; ++nt) {
        int n = nt * 16 + n16;
        #pragma unroll
        for (int kh = 0; kh < 2; ++kh) {
            short8 f = {0, 0, 0, 0, 0, 0, 0, 0};
            if (n < 54) {
                const float* src = (n < 27) ? (rph + (size_t)n * HD)
                                            : (rpw + (size_t)(n - 27) * HD);
                const float4* s4 = (const float4*)(src + kh * 32 + quad * 8);
                float4 a = s4[0], b = s4[1];
                f[0] = (short)f2bu(a.x); f[1] = (short)f2bu(a.y);
                f[2] = (short)f2bu(a.z); f[3] = (short)f2bu(a.w);
                f[4] = (short)f2bu(b.x); f[5] = (short)f2bu(b.y);
                f[6] = (short)f2bu(b.z); f[7] = (short)f2bu(b.w);
            }
            btab[nt][kh] = f;
        }
    }

    // ---- stage K: 196 rows x 64 bf16 ----
    for (int idx = tid; idx < 1568; idx += 256) {
        int row = idx >> 3, q8 = (idx & 7) << 3;
        *(uint4*)&Ks[row * 72 + q8] = *(const uint4*)(k + (size_t)row * HD + q8);
    }
    // ---- stage V transposed: Vt[d][tok] (coalesced: d = lane) ----
    for (int s = tid; s < 49 * 64; s += 256) {
        int g = s >> 6, d = s & 63;
        unsigned int w0 = ((unsigned int)v[(size_t)(4 * g + 0) * HD + d]) |
                          ((unsigned int)v[(size_t)(4 * g + 1) * HD + d] << 16);
        unsigned int w1 = ((unsigned int)v[(size_t)(4 * g + 2) * HD + d]) |
                          ((unsigned int)v[(size_t)(4 * g + 3) * HD + d] << 16);
        uint2 pk = {w0, w1};
        *(uint2*)&Vt[d * 224 + 4 * g] = pk;
    }
    for (int s = tid; s < 448; s += 256) {      // zero cols 196..223
        int r = s / 7, c = 196 + (s - r * 7) * 4;
        uint2 z = {0u, 0u};
        *(uint2*)&Vt[r * 224 + c] = z;
    }
    __syncthreads();

    unsigned short* myscr = &scr[wave * 864];
    int rl0 = quad * 4;

    for (int qt = wave; qt < 13; qt += 4) {
        int qrow = qt * 16 + n16;
        int qr = qrow < 196 ? qrow : 195;

        short8 qf0 = *(const short8*)(q + (size_t)qr * HD + quad * 8);
        short8 qf1 = *(const short8*)(q + (size_t)qr * HD + 32 + quad * 8);

        // rel bias via MFMA: rel[16 rows][54 cols] -> scr (C-layout rows match)
        #pragma unroll
        for (int nt = 0; nt < 4; ++nt) {
            floatx4 cr = {0.f, 0.f, 0.f, 0.f};
            cr = __builtin_amdgcn_mfma_f32_16x16x32_bf16(qf0, btab[nt][0], cr, 0, 0, 0);
            cr = __builtin_amdgcn_mfma_f32_16x16x32_bf16(qf1, btab[nt][1], cr, 0, 0, 0);
            int c = nt * 16 + n16;
            if (c < 54) {
                #pragma unroll
                for (int r = 0; r < 4; ++r)
                    myscr[(rl0 + r) * 54 + c] = f2bu(cr[r]);
            }
        }

        // S = Q K^T (13 n-tiles in registers)
        floatx4 S[13];
        #pragma unroll
        for (int nt = 0; nt < 13; ++nt) {
            short8 kf0 = *(const short8*)&Ks[(nt * 16 + n16) * 72 + quad * 8];
            short8 kf1 = *(const short8*)&Ks[(nt * 16 + n16) * 72 + 32 + quad * 8];
            floatx4 a = {0.f, 0.f, 0.f, 0.f};
            a = __builtin_amdgcn_mfma_f32_16x16x32_bf16(qf0, kf0, a, 0, 0, 0);
            a = __builtin_amdgcn_mfma_f32_16x16x32_bf16(qf1, kf1, a, 0, 0, 0);
            S[nt] = a;
        }

        // per-row coords (rows rl0+r of this q-tile)
        int ti4[4], tj4[4];
        #pragma unroll
        for (int r = 0; r < 4; ++r) {
            int grow = qt * 16 + rl0 + r;
            ti4[r] = grow / WSZ;
            tj4[r] = grow - ti4[r] * WSZ;
        }

        // scale + rel bias + mask pad cols
        #pragma unroll
        for (int nt = 0; nt < 13; ++nt) {
            int col = nt * 16 + n16;
            int ki = col / WSZ, kj = col - ki * WSZ;
            #pragma unroll
            for (int r = 0; r < 4; ++r) {
                float rh = bf2f(myscr[(rl0 + r) * 54 + (ti4[r] - ki + 13)]);
                float rw = bf2f(myscr[(rl0 + r) * 54 + (40 + tj4[r] - kj)]);
                S[nt][r] = fmaf(S[nt][r], 0.125f, rh + rw);
            }
        }
        if (n16 >= 4) {
            #pragma unroll
            for (int r = 0; r < 4; ++r) S[12][r] = -1e30f;
        }

        // row softmax (rows spread across the 16 n16 lanes)
        float mxr[4] = {-3e30f, -3e30f, -3e30f, -3e30f};
        #pragma unroll
        for (int nt = 0; nt < 13; ++nt)
            #pragma unroll
            for (int r = 0; r < 4; ++r) mxr[r] = fmaxf(mxr[r], S[nt][r]);
        #pragma unroll
        for (int m = 1; m <= 8; m <<= 1)
            #pragma unroll
            for (int r = 0; r < 4; ++r) mxr[r] = fmaxf(mxr[r], __shfl_xor(mxr[r], m, 64));
        float sum[4] = {0.f, 0.f, 0.f, 0.f};
        #pragma unroll
        for (int nt = 0; nt < 13; ++nt)
            #pragma unroll
            for (int r = 0; r < 4; ++r) {
                float e = __expf(S[nt][r] - mxr[r]);
                S[nt][r] = e;
                sum[r] += e;
            }
        #pragma unroll
        for (int m = 1; m <= 8; m <<= 1)
            #pragma unroll
            for (int r = 0; r < 4; ++r) sum[r] += __shfl_xor(sum[r], m, 64);
        float inv[4];
        #pragma unroll
        for (int r = 0; r < 4; ++r) inv[r] = 1.0f / sum[r];

        // O = P V (P round-trips through per-wave scratch into A-layout)
        floatx4 O[4] = {{0.f,0.f,0.f,0.f},{0.f,0.f,0.f,0.f},{0.f,0.f,0.f,0.f},{0.f,0.f,0.f,0.f}};
        #pragma unroll
        for (int ks = 0; ks < 7; ++ks) {
            #pragma unroll
            for (int r = 0; r < 4; ++r) {
                myscr[(rl0 + r) * 40 + n16] = f2bu(S[2 * ks][r] * inv[r]);
                myscr[(rl0 + r) * 40 + 16 + n16] =
                    (2 * ks + 1 < 13) ? f2bu(S[2 * ks + 1][r] * inv[r]) : (unsigned short)0;
            }
            short8 pf = *(const short8*)&myscr[n16 * 40 + quad * 8];
            #pragma unroll
            for (int nt4 = 0; nt4 < 4; ++nt4) {
                short8 vf = *(const short8*)&Vt[(nt4 * 16 + n16) * 224 + ks * 32 + quad * 8];
                O[nt4] = __builtin_amdgcn_mfma_f32_16x16x32_bf16(pf, vf, O[nt4], 0, 0, 0);
            }
        }

        // store O tile (rows quad*4+r, cols d = nt4*16+n16)
        #pragma unroll
        for (int nt4 = 0; nt4 < 4; ++nt4) {
            int d = nt4 * 16 + n16;
            #pragma unroll
            for (int r = 0; r < 4; ++r) {
                int row = qt * 16 + rl0 + r;
                if (row < 196) {
                    ao[((size_t)(lwin * TOK + row)) * HS + head * HD + d] =
                        __float2bfloat16(O[nt4][r]);
                }
            }
        }
    }
}

extern "C" void kernel_launch(void* const* d_in, const int* in_sizes, int n_in,
                              void* d_out, int out_size, void* d_ws, size_t ws_size,
                              hipStream_t stream)
{
    const float* x      = (const float*)d_in[0];
    const float* ln1_g  = (const float*)d_in[1];
    const float* ln1_b  = (const float*)d_in[2];
    const float* qkv_w  = (const float*)d_in[3];
    const float* qkv_b  = (const float*)d_in[4];
    const float* proj_w = (const float*)d_in[5];
    const float* proj_b = (const float*)d_in[6];
    const float* rph    = (const float*)d_in[7];
    const float* rpw    = (const float*)d_in[8];
    const float* ln2_g  = (const float*)d_in[9];
    const float* ln2_b  = (const float*)d_in[10];
    const float* mlp_w1 = (const float*)d_in[11];
    const float* mlp_b1 = (const float*)d_in[12];
    const float* mlp_w2 = (const float*)d_in[13];
    const float* mlp_b2 = (const float*)d_in[14];
    float* out = (float*)d_out;

    char* ws = (char*)d_ws;
    __hip_bfloat16* wqkv  = (__hip_bfloat16*)(ws + 0);          // [2304][768]
    __hip_bfloat16* wproj = (__hip_bfloat16*)(ws + 3538944);    // [768][768]
    __hip_bfloat16* wm1   = (__hip_bfloat16*)(ws + 4718592);    // [3072][768]
    __hip_bfloat16* wm2   = (__hip_bfloat16*)(ws + 9437184);    // [768][3072]
    __hip_bfloat16* ybuf  = (__hip_bfloat16*)(ws + 14155776);   // 32768x768
    char* R2 = ws + 64487424;
    __hip_bfloat16* qc  = (__hip_bfloat16*)(R2);
    __hip_bfloat16* kc  = (__hip_bfloat16*)(R2 + 7526400);
    __hip_bfloat16* vc  = (__hip_bfloat16*)(R2 + 15052800);
    __hip_bfloat16* ao  = (__hip_bfloat16*)(R2 + 22579200);
    __hip_bfloat16* hid = (__hip_bfloat16*)(R2);

    cvt_t_k<<<dim3(6912), 256, 0, stream>>>(qkv_w,  wqkv,  768, 2304);
    cvt_t_k<<<dim3(2304), 256, 0, stream>>>(proj_w, wproj, 768, 768);
    cvt_t_k<<<dim3(9216), 256, 0, stream>>>(mlp_w1, wm1,   768, 3072);
    cvt_t_k<<<dim3(9216), 256, 0, stream>>>(mlp_w2, wm2,  3072, 768);

    ln_k<<<dim3(32768), 256, 0, stream>>>(x, ln1_g, ln1_b, ybuf);

    for (int wc = 0; wc < 8; ++wc) {
        gemm_k<0, 1><<<dim3(77, 36), 256, 0, stream>>>(
            ybuf, wqkv, qkv_b, MCH, 2304, 768,
            qc, kc, vc, nullptr, nullptr, nullptr, wc * WCHUNK, 0);
        attn_k<<<dim3(300), 256, 0, stream>>>(qc, kc, vc, rph, rpw, ao);
        gemm_k<1, 0><<<dim3(77, 12), 256, 0, stream>>>(
            ao, wproj, proj_b, MCH, 768, 768,
            nullptr, nullptr, nullptr, out, x, nullptr, wc * WCHUNK, 0);
    }

    ln_k<<<dim3(32768), 256, 0, stream>>>(out, ln2_g, ln2_b, ybuf);

    for (int mc = 0; mc < 4; ++mc) {
        gemm_k<2, 0><<<dim3(128, 48), 256, 0, stream>>>(
            ybuf + (size_t)mc * MLPCH * HS, wm1, mlp_b1, MLPCH, 3072, 768,
            nullptr, nullptr, nullptr, nullptr, nullptr, hid, 0, 0);
        gemm_k<3, 0><<<dim3(128, 12), 256, 0, stream>>>(
            hid, wm2, mlp_b2, MLPCH, 768, 3072,
            nullptr, nullptr, nullptr, out, nullptr, nullptr, 0, mc * MLPCH);
    }
}